// Round 13
// baseline (244.578 us; speedup 1.0000x reference)
//
#include <hip/hip_runtime.h>
#include <math.h>

// Problem constants
#define BB 8
#define LL 1024
#define SS 1024
#define CC 128
#define NN 8
#define PP 256

static constexpr float EPS       = 1e-6f;
static constexpr float ONE_M_EPS = 1.0f - 1e-6f;
static constexpr float INV_T     = 1.0f / 0.07f;
static constexpr float NLL_MAX   = 13.815511f;    // -log(1e-6)
static constexpr float NLL_MIN   = 1.0000005e-6f; // -log(1-1e-6)

// Workspace layout (float offsets) — no dot array (acc stays on-chip)
static constexpr size_t OFF_LSER   = 0;                      // 8192
static constexpr size_t OFF_LSEC   = 8192;                   // 8192
static constexpr size_t OFF_SHARP2 = 16384;                  // 8192
static constexpr size_t OFF_RP     = 24576;                  // 8*32*1024*4 = 1048576
static constexpr size_t OFF_CP     = OFF_RP + 1048576;       // 8*16*1024*4 = 524288
static constexpr size_t OFF_ACC    = OFF_CP + 524288;        // 48 + 2
static constexpr size_t OFF_ACCCL  = OFF_ACC + 48;
static constexpr size_t OFF_SYNC   = OFF_ACC + 64;           // 4 uints
static constexpr size_t OFF_QN     = OFF_ACC + 128;          // 1024
static constexpr size_t OFF_R2     = OFF_QN + 1024;          // 16*18 combine scratch
static constexpr size_t OFF_R3     = OFF_R2 + 512;           // 512*48 loss scratch

static constexpr unsigned MAGIC = 0x1337C0DEu;  // distinct bytes: can't equal byte-repeated poison

// Output layout (floats): sharp1[8192], cl_pos_save[1024], scalars
static constexpr int OUT_CLSAVE = 8192;
static constexpr int OUT_SCAL   = 9216;

typedef __bf16 bf16x8 __attribute__((ext_vector_type(8)));
typedef float  floatx4 __attribute__((ext_vector_type(4)));

// Split 4 fp32 into packed bf16 hi pairs (RNE) + lo pairs (exact residual, truncated).
__device__ __forceinline__ void split_f4(float4 x,
                                         unsigned& hp0, unsigned& hp1,
                                         unsigned& lp0, unsigned& lp1) {
    unsigned u0 = __builtin_bit_cast(unsigned, x.x);
    unsigned u1 = __builtin_bit_cast(unsigned, x.y);
    unsigned u2 = __builtin_bit_cast(unsigned, x.z);
    unsigned u3 = __builtin_bit_cast(unsigned, x.w);
    unsigned r0 = u0 + 0x7FFFu + ((u0 >> 16) & 1u);
    unsigned r1 = u1 + 0x7FFFu + ((u1 >> 16) & 1u);
    unsigned r2 = u2 + 0x7FFFu + ((u2 >> 16) & 1u);
    unsigned r3 = u3 + 0x7FFFu + ((u3 >> 16) & 1u);
    float s0 = x.x - __builtin_bit_cast(float, r0 & 0xFFFF0000u);
    float s1 = x.y - __builtin_bit_cast(float, r1 & 0xFFFF0000u);
    float s2 = x.z - __builtin_bit_cast(float, r2 & 0xFFFF0000u);
    float s3 = x.w - __builtin_bit_cast(float, r3 & 0xFFFF0000u);
    hp0 = __builtin_amdgcn_perm(r1, r0, 0x07060302u);
    hp1 = __builtin_amdgcn_perm(r3, r2, 0x07060302u);
    lp0 = __builtin_amdgcn_perm(__builtin_bit_cast(unsigned, s1),
                                __builtin_bit_cast(unsigned, s0), 0x07060302u);
    lp1 = __builtin_amdgcn_perm(__builtin_bit_cast(unsigned, s3),
                                __builtin_bit_cast(unsigned, s2), 0x07060302u);
}

// Grid barrier: agent-scope atomics at the (XCD-coherent) LLC. ACQ_REL add flushes
// this block's L2 (release); final ACQUIRE load invalidates for fresh reads.
__device__ __forceinline__ void gsync(unsigned* sc, int id) {
    __syncthreads();
    if (threadIdx.x == 0) {
        unsigned* c = sc + id;
        __hip_atomic_fetch_add(c, 1u, __ATOMIC_ACQ_REL, __HIP_MEMORY_SCOPE_AGENT);
        while (__hip_atomic_load(c, __ATOMIC_RELAXED, __HIP_MEMORY_SCOPE_AGENT) < 512u)
            __builtin_amdgcn_s_sleep(8);
        (void)__hip_atomic_load(c, __ATOMIC_ACQUIRE, __HIP_MEMORY_SCOPE_AGENT);
    }
    __syncthreads();
}

__device__ __forceinline__ void proc_elem(float d, int lab, float lcj, float sh1j,
                                          float lr, float s2v,
                                          float& posg, float& negg, float& l1, float& l2,
                                          float& negs, float& pcf) {
    float t = lr + lcj - d * (2.0f * INV_T);   // -log(conf_geo)
    bool  pos   = (lab == 1);
    float isPos = pos ? 1.0f : 0.0f;
    float isNeg = 1.0f - isPos;
    float tp   = fminf(fmaxf(t, NLL_MIN), NLL_MAX);
    float simc = fminf(fmaxf(fmaf(0.5f, d, 0.5f), EPS), ONE_M_EPS);
    float om   = fminf(fmaxf(fmaf(-0.5f, d, 0.5f), EPS), ONE_M_EPS);   // 1-simc exactly
    float x    = pos ? simc : om;
    float nllx = -__logf(x);
    float cf   = fminf(fmaxf(__expf(-t), EPS), ONE_M_EPS);
    float wi   = pos ? 1.0f : (1.0f - cf);
    float nllw = -__logf(wi);
    posg += isPos * tp;
    l1   += isPos * nllx * sh1j;
    l2   += isPos * nllx * s2v;
    pcf  += isPos;
    negg += isNeg * nllw;
    negs += isNeg * nllx;
}

// ================= MEGA KERNEL: gemm+stats | combine+softmax+contrast | loss | finalize =========
__global__ __launch_bounds__(512, 4) void mega(const float* __restrict__ A,
                                               const float* __restrict__ Bm,
                                               const float* __restrict__ q_cl,
                                               const float* __restrict__ cl_pos,
                                               const int* __restrict__ label,
                                               const int* __restrict__ idx,
                                               float* __restrict__ out,
                                               float* __restrict__ ws) {
    __shared__ __align__(16) char lds[65536];

    int tid  = threadIdx.x;
    int lane = tid & 63;
    int w    = tid >> 6;                // 0..7
    int t    = blockIdx.x;              // 0..511
    unsigned* sc = (unsigned*)(ws + OFF_SYNC);

    // ---- Phase 0: gate. Block 0 re-inits counters/accumulators (ws is re-poisoned each iter). ----
    if (t == 0) {
        if (tid == 0) {
            __hip_atomic_store(sc + 1, 0u, __ATOMIC_RELAXED, __HIP_MEMORY_SCOPE_AGENT);
            __hip_atomic_store(sc + 2, 0u, __ATOMIC_RELAXED, __HIP_MEMORY_SCOPE_AGENT);
            __hip_atomic_store(sc + 3, 0u, __ATOMIC_RELAXED, __HIP_MEMORY_SCOPE_AGENT);
            __hip_atomic_store(sc + 0, MAGIC, __ATOMIC_RELEASE, __HIP_MEMORY_SCOPE_AGENT);
        }
        if (tid < 50)
            __hip_atomic_store(ws + OFF_ACC + tid, 0.0f, __ATOMIC_RELAXED, __HIP_MEMORY_SCOPE_AGENT);
        // prep: 8 waves, wave n normalizes q_sel[n], writes cl_pos_save
        {
            int n = w;
            int in = idx[n];
            const float* q = q_cl + ((size_t)(n * PP + in)) * CC;
            float2 qv = *(const float2*)(q + 2 * lane);
            float ss = qv.x * qv.x + qv.y * qv.y;
            for (int o = 32; o; o >>= 1) ss += __shfl_xor(ss, o);
            float inv = 1.0f / fmaxf(sqrtf(ss), 1e-12f);
            *(float2*)(ws + OFF_QN + n * 128 + 2 * lane) = make_float2(qv.x * inv, qv.y * inv);
            const float* cp = cl_pos + ((size_t)(n * PP + in)) * CC;
            float2 cv = *(const float2*)(cp + 2 * lane);
            *(float2*)(out + OUT_CLSAVE + n * 128 + 2 * lane) = cv;
        }
    } else if (tid == 0) {
        while (__hip_atomic_load(sc, __ATOMIC_RELAXED, __HIP_MEMORY_SCOPE_AGENT) != MAGIC)
            __builtin_amdgcn_s_sleep(8);
        (void)__hip_atomic_load(sc, __ATOMIC_ACQUIRE, __HIP_MEMORY_SCOPE_AGENT);
    }
    __syncthreads();

    // ---- Phase 1: GEMM 128x128 tile (half-K phases, round-12 structure) + tile stats ----
    int b  = t >> 6;
    int rm = t & 63;
    int bl = rm >> 3, bs = rm & 7;
    int R0 = bl * 128, C0 = bs * 128;

    const float* Ab = A  + ((size_t)(b * 1024 + R0)) * CC;
    const float* Bb = Bm + ((size_t)(b * 1024 + C0)) * CC;

    const float* srcu[2];
    int hib[2], lob[2];
#pragma unroll
    for (int u = 0; u < 2; u++) {
        int g   = u * 512 + tid;
        int mat = g >> 9;
        int r   = (g >> 2) & 127;
        int c8  = g & 3;
        srcu[u] = (mat ? Bb : Ab) + (size_t)r * CC + c8 * 8;
        int base = mat * 16384 + r * 128;
        int sw   = r & 7;
        hib[u] = base + ((c8 ^ sw) * 16);
        lob[u] = base + (((c8 + 4) ^ sw) * 16);
    }

    int fl   = lane & 15;
    int quad = lane >> 4;
    int wr   = w >> 2, wc = w & 3;      // 2x4 wave grid
    int Rw   = wr * 64, Cw = wc * 32;   // wave's 64x32 output

    {
        floatx4 acc[4][2];
#pragma unroll
        for (int i = 0; i < 4; i++)
#pragma unroll
            for (int j = 0; j < 2; j++) acc[i][j] = (floatx4){0.f, 0.f, 0.f, 0.f};

        float4 e0[2], e1[2], o0[2], o1[2];
#pragma unroll
        for (int u = 0; u < 2; u++) {
            e0[u] = *(const float4*)(srcu[u]);
            e1[u] = *(const float4*)(srcu[u] + 4);
            o0[u] = *(const float4*)(srcu[u] + 32);
            o1[u] = *(const float4*)(srcu[u] + 36);
        }
#pragma unroll
        for (int u = 0; u < 2; u++) {
            unsigned h0, h1, h2, h3, l0, l1, l2, l3;
            split_f4(e0[u], h0, h1, l0, l1); split_f4(e1[u], h2, h3, l2, l3);
            *(uint4*)(&lds[hib[u]]) = make_uint4(h0, h1, h2, h3);
            *(uint4*)(&lds[lob[u]]) = make_uint4(l0, l1, l2, l3);
            split_f4(o0[u], h0, h1, l0, l1); split_f4(o1[u], h2, h3, l2, l3);
            *(uint4*)(&lds[32768 + hib[u]]) = make_uint4(h0, h1, h2, h3);
            *(uint4*)(&lds[32768 + lob[u]]) = make_uint4(l0, l1, l2, l3);
        }
        __syncthreads();

#pragma unroll
        for (int half = 0; half < 2; half++) {
            if (half == 0) {
#pragma unroll
                for (int u = 0; u < 2; u++) {
                    e0[u] = *(const float4*)(srcu[u] + 64);
                    e1[u] = *(const float4*)(srcu[u] + 68);
                    o0[u] = *(const float4*)(srcu[u] + 96);
                    o1[u] = *(const float4*)(srcu[u] + 100);
                }
            }
#pragma unroll
            for (int kk = 0; kk < 2; kk++) {
                const char* la = lds + kk * 32768;
                const char* lb = la + 16384;
                bf16x8 ah[4], al[4];
#pragma unroll
                for (int mt = 0; mt < 4; mt++) {
                    int row = Rw + mt * 16 + fl;
                    int sw  = row & 7;
                    ah[mt] = *(const bf16x8*)(la + row * 128 + ((quad ^ sw) * 16));
                    al[mt] = *(const bf16x8*)(la + row * 128 + (((quad + 4) ^ sw) * 16));
                }
#pragma unroll
                for (int nt = 0; nt < 2; nt++) {
                    int row = Cw + nt * 16 + fl;
                    int sw  = row & 7;
                    bf16x8 bh  = *(const bf16x8*)(lb + row * 128 + ((quad ^ sw) * 16));
                    bf16x8 blo = *(const bf16x8*)(lb + row * 128 + (((quad + 4) ^ sw) * 16));
#pragma unroll
                    for (int mt = 0; mt < 4; mt++) {
                        acc[mt][nt] = __builtin_amdgcn_mfma_f32_16x16x32_bf16(ah[mt], bh,  acc[mt][nt], 0, 0, 0);
                        acc[mt][nt] = __builtin_amdgcn_mfma_f32_16x16x32_bf16(ah[mt], blo, acc[mt][nt], 0, 0, 0);
                        acc[mt][nt] = __builtin_amdgcn_mfma_f32_16x16x32_bf16(al[mt], bh,  acc[mt][nt], 0, 0, 0);
                    }
                }
            }
            __syncthreads();
            if (half == 0) {
#pragma unroll
                for (int u = 0; u < 2; u++) {
                    unsigned h0, h1, h2, h3, l0, l1, l2, l3;
                    split_f4(e0[u], h0, h1, l0, l1); split_f4(e1[u], h2, h3, l2, l3);
                    *(uint4*)(&lds[hib[u]]) = make_uint4(h0, h1, h2, h3);
                    *(uint4*)(&lds[lob[u]]) = make_uint4(l0, l1, l2, l3);
                    split_f4(o0[u], h0, h1, l0, l1); split_f4(o1[u], h2, h3, l2, l3);
                    *(uint4*)(&lds[32768 + hib[u]]) = make_uint4(h0, h1, h2, h3);
                    *(uint4*)(&lds[32768 + lob[u]]) = make_uint4(l0, l1, l2, l3);
                }
                __syncthreads();
            }
        }

        // park acc in LDS (128x128 f32 tile) for phase 3
        float* Lf = (float*)lds;
#pragma unroll
        for (int mt = 0; mt < 4; mt++)
#pragma unroll
            for (int nt = 0; nt < 2; nt++) {
                int cl = Cw + nt * 16 + fl;
#pragma unroll
                for (int r = 0; r < 4; r++)
                    Lf[(Rw + mt * 16 + quad * 4 + r) * 128 + cl] = acc[mt][nt][r];
            }

        // ---- tile stats (from registers) ----
        int stile = bs * 4 + wc;
        int ltile = bl * 2 + wr;
        float ces[2], cmx[2], csm[2], csq[2];
#pragma unroll
        for (int nt = 0; nt < 2; nt++) { ces[nt] = 0.f; cmx[nt] = -1e30f; csm[nt] = 0.f; csq[nt] = 0.f; }
#pragma unroll
        for (int mt = 0; mt < 4; mt++) {
#pragma unroll
            for (int r = 0; r < 4; r++) {
                float es = 0.f, mx = -1e30f, sm = 0.f, sq = 0.f;
#pragma unroll
                for (int nt = 0; nt < 2; nt++) {
                    float d  = acc[mt][nt][r];
                    float e  = __expf(d * INV_T);
                    float s2 = fmaf(0.5f, d, 0.5f);
                    es += e; mx = fmaxf(mx, s2); sm += s2; sq += s2 * s2;
                    ces[nt] += e; cmx[nt] = fmaxf(cmx[nt], s2); csm[nt] += s2; csq[nt] += s2 * s2;
                }
                for (int o = 1; o < 16; o <<= 1) {
                    es += __shfl_xor(es, o);
                    mx = fmaxf(mx, __shfl_xor(mx, o));
                    sm += __shfl_xor(sm, o);
                    sq += __shfl_xor(sq, o);
                }
                if (fl == 0) {
                    int row = R0 + Rw + mt * 16 + quad * 4 + r;
                    *(float4*)(ws + OFF_RP + (((size_t)(b * 32 + stile)) * 1024 + row) * 4) =
                        make_float4(es, mx, sm, sq);
                }
            }
        }
#pragma unroll
        for (int nt = 0; nt < 2; nt++) {
            float es = ces[nt], mx = cmx[nt], sm = csm[nt], sq = csq[nt];
            for (int o = 16; o < 64; o <<= 1) {
                es += __shfl_xor(es, o);
                mx = fmaxf(mx, __shfl_xor(mx, o));
                sm += __shfl_xor(sm, o);
                sq += __shfl_xor(sq, o);
            }
            if (quad == 0) {
                int col = C0 + Cw + nt * 16 + fl;
                *(float4*)(ws + OFF_CP + (((size_t)(b * 16 + ltile)) * 1024 + col) * 4) =
                    make_float4(es, mx, sm, sq);
            }
        }
    }

    gsync(sc, 1);

    // ---- Phase 2: blocks 0-15 combine+softmax (global scratch, no LDS); 16-80 contrast ----
    if (t < 16) {
        bool docol = (t < 8);
        int bq = t & 7;
        const float* pb = ws + (docol ? (OFF_CP + (size_t)bq * 16 * 1024 * 4)
                                      : (OFF_RP + (size_t)bq * 32 * 1024 * 4));
        float* lse = ws + (docol ? OFF_LSEC : OFF_LSER) + (size_t)bq * 1024;
        float* red = ws + OFF_R2 + (size_t)t * 18;
        float zs[2];
        float mxall = -1e30f;
#pragma unroll
        for (int r = 0; r < 2; r++) {
            int i = tid + r * 512;
            const float* base = pb + (size_t)i * 4;
            float es = 0.f, mx = -1e30f, sm = 0.f, sq = 0.f;
#pragma unroll
            for (int tt = 0; tt < 16; tt++) {
                float4 v = *(const float4*)(base + (size_t)tt * 4096);
                es += v.x; mx = fmaxf(mx, v.y); sm += v.z; sq += v.w;
            }
            if (!docol) {
#pragma unroll
                for (int tt = 16; tt < 32; tt++) {
                    float4 v = *(const float4*)(base + (size_t)tt * 4096);
                    es += v.x; mx = fmaxf(mx, v.y); sm += v.z; sq += v.w;
                }
            }
            float mean = sm * (1.0f / 1024.0f);
            float var  = (sq - sm * sm * (1.0f / 1024.0f)) * (1.0f / 1023.0f);
            zs[r] = (mx - mean) / sqrtf(fmaxf(var, 1e-30f));
            mxall = fmaxf(mxall, zs[r]);
            lse[i] = __logf(es);
        }
        float mx = mxall;
        for (int o = 32; o; o >>= 1) mx = fmaxf(mx, __shfl_xor(mx, o));
        if (!lane) red[w] = mx;
        __syncthreads();
        if (tid == 0) {
            float m = red[0];
            for (int k = 1; k < 8; k++) m = fmaxf(m, red[k]);
            red[16] = m;
        }
        __syncthreads();
        mx = red[16];
        float e[2]; float smv = 0.f;
#pragma unroll
        for (int r = 0; r < 2; r++) { e[r] = __expf(zs[r] - mx); smv += e[r]; }
        for (int o = 32; o; o >>= 1) smv += __shfl_xor(smv, o);
        if (!lane) red[8 + w] = smv;
        __syncthreads();
        if (tid == 0) {
            float s = red[8];
            for (int k = 1; k < 8; k++) s += red[8 + k];
            red[17] = s;
        }
        __syncthreads();
        float inv = 1.0f / red[17];
        float* dst = docol ? (out + (size_t)bq * 1024) : (ws + OFF_SHARP2 + (size_t)bq * 1024);
#pragma unroll
        for (int r = 0; r < 2; r++) dst[tid + r * 512] = e[r] * inv;
    } else if (t < 81) {
        // contrast: wave w handles j = (t-16)*8 + w  (0..519)
        int j = (t - 16) * 8 + w;
        int m, p;
        if (j < NN) {
            m = j; p = idx[j];
        } else {
            int jj = j - NN;
            m = jj / (PP - 1);
            p = 1 + (jj - m * (PP - 1));
            if (p == idx[m]) p = 0;
        }
        const float* k = cl_pos + ((size_t)(m * PP + p)) * CC;
        float2 kv = *(const float2*)(k + 2 * lane);
        float ksq = kv.x * kv.x + kv.y * kv.y;
        for (int o = 32; o; o >>= 1) ksq += __shfl_xor(ksq, o);
        float invkn = 1.0f / fmaxf(sqrtf(ksq), 1e-12f);
        if (j < NN) {
            const float2 qv = *(const float2*)(ws + OFF_QN + j * 128 + 2 * lane);
            float dt = qv.x * kv.x + qv.y * kv.y;
            for (int o = 32; o; o >>= 1) dt += __shfl_xor(dt, o);
            float sim = fminf(fmaxf(fmaf(0.5f * invkn, dt, 0.5f), EPS), ONE_M_EPS);
            if (lane == 0) atomicAdd(ws + OFF_ACCCL + 0, -__logf(sim));
        } else {
            float neg = 0.0f;
#pragma unroll
            for (int n = 0; n < NN; n++) {
                const float2 qv = *(const float2*)(ws + OFF_QN + n * 128 + 2 * lane);
                float dt = qv.x * kv.x + qv.y * kv.y;
                for (int o = 32; o; o >>= 1) dt += __shfl_xor(dt, o);
                float om = fminf(fmaxf(fmaf(-0.5f * invkn, dt, 0.5f), EPS), ONE_M_EPS);
                neg -= __logf(om);
            }
            if (lane == 0) atomicAdd(ws + OFF_ACCCL + 1, neg);
        }
    }

    gsync(sc, 2);

    // ---- Phase 3: loss on own tile. acc from LDS tile; label staged via LDS (coalesced HBM). ----
    {
        float* Lf = (float*)lds;
        floatx4 acc[4][2];
#pragma unroll
        for (int mt = 0; mt < 4; mt++)
#pragma unroll
            for (int nt = 0; nt < 2; nt++) {
                int cl = Cw + nt * 16 + fl;
#pragma unroll
                for (int r = 0; r < 4; r++)
                    acc[mt][nt][r] = Lf[(Rw + mt * 16 + quad * 4 + r) * 128 + cl];
            }
        __syncthreads();

        int* Li = (int*)lds;
        const int* lrow = label + ((size_t)(b * 1024 + R0)) * 1024 + C0;
#pragma unroll
        for (int it = 0; it < 8; it++) {
            int g  = it * 512 + tid;
            int rr = g >> 5;
            int cc = (g & 31) * 4;
            *(int4*)(Li + rr * 128 + cc) = *(const int4*)(lrow + (size_t)rr * 1024 + cc);
        }
        __syncthreads();

        floatx4 lr4[4], s24[4];
#pragma unroll
        for (int mt = 0; mt < 4; mt++) {
            int row = R0 + Rw + mt * 16 + quad * 4;
            lr4[mt] = *(const floatx4*)(ws + OFF_LSER + (size_t)b * 1024 + row);
            s24[mt] = *(const floatx4*)(ws + OFF_SHARP2 + (size_t)b * 1024 + row);
        }
        float lcv[2], sh1v[2];
#pragma unroll
        for (int nt = 0; nt < 2; nt++) {
            int col = C0 + Cw + nt * 16 + fl;
            lcv[nt]  = ws[OFF_LSEC + (size_t)b * 1024 + col];
            sh1v[nt] = out[(size_t)b * 1024 + col];
        }

        float posg = 0, negg = 0, l1 = 0, l2 = 0, negs = 0, pcf = 0;
#pragma unroll
        for (int mt = 0; mt < 4; mt++)
#pragma unroll
            for (int r = 0; r < 4; r++) {
                int rl = (Rw + mt * 16 + quad * 4 + r) * 128;
#pragma unroll
                for (int nt = 0; nt < 2; nt++) {
                    int lab = Li[rl + Cw + nt * 16 + fl];
                    proc_elem(acc[mt][nt][r], lab, lcv[nt], sh1v[nt], lr4[mt][r], s24[mt][r],
                              posg, negg, l1, l2, negs, pcf);
                }
            }

        float vals[6] = {posg, negg, l1, l2, negs, pcf};
        float* red3 = ws + OFF_R3 + (size_t)t * 48;
#pragma unroll
        for (int k = 0; k < 6; k++) {
            float v = vals[k];
            for (int o = 32; o; o >>= 1) v += __shfl_xor(v, o);
            if (!lane) red3[k * 8 + w] = v;
        }
        __syncthreads();
        if (tid < 6) {
            float r = 0.f;
#pragma unroll
            for (int k = 0; k < 8; k++) r += red3[tid * 8 + k];
            atomicAdd(ws + OFF_ACC + (size_t)b * 6 + tid, r);
        }
    }

    gsync(sc, 3);

    // ---- Phase 4: finalize (block 0, thread 0) ----
    if (t == 0 && tid == 0) {
        float gp = 0, gn = 0, lsh = 0;
        for (int b2 = 0; b2 < 8; b2++) {
            float a0 = __hip_atomic_load(ws + OFF_ACC + b2 * 6 + 0, __ATOMIC_RELAXED, __HIP_MEMORY_SCOPE_AGENT);
            float a1 = __hip_atomic_load(ws + OFF_ACC + b2 * 6 + 1, __ATOMIC_RELAXED, __HIP_MEMORY_SCOPE_AGENT);
            float a2 = __hip_atomic_load(ws + OFF_ACC + b2 * 6 + 2, __ATOMIC_RELAXED, __HIP_MEMORY_SCOPE_AGENT);
            float a3 = __hip_atomic_load(ws + OFF_ACC + b2 * 6 + 3, __ATOMIC_RELAXED, __HIP_MEMORY_SCOPE_AGENT);
            float a4 = __hip_atomic_load(ws + OFF_ACC + b2 * 6 + 4, __ATOMIC_RELAXED, __HIP_MEMORY_SCOPE_AGENT);
            float pc = __hip_atomic_load(ws + OFF_ACC + b2 * 6 + 5, __ATOMIC_RELAXED, __HIP_MEMORY_SCOPE_AGENT);
            float nc = (float)((size_t)LL * SS) - pc;
            gp += a0 / fmaxf(pc, 1.0f);
            gn += a1 / fmaxf(nc, 1.0f);
            lsh += (a2 + a3) * 0.5f + a4 / fmaxf(nc, 1.0f);
        }
        gp *= 0.125f; gn *= 0.125f; lsh *= 0.125f;
        float lgeo = gp + gn;
        float lgw = (0.5f * lgeo + 0.5f * lsh) * 0.5f;
        float clp = __hip_atomic_load(ws + OFF_ACCCL + 0, __ATOMIC_RELAXED, __HIP_MEMORY_SCOPE_AGENT) / 8.0f;
        float cln = __hip_atomic_load(ws + OFF_ACCCL + 1, __ATOMIC_RELAXED, __HIP_MEMORY_SCOPE_AGENT) / (8.0f * 2040.0f);
        float lcl = (clp + cln) * 0.5f * 0.5f;
        out[OUT_SCAL + 0] = lgw + lcl;  // total
        out[OUT_SCAL + 1] = gp;         // geo_pos_loss
        out[OUT_SCAL + 2] = gn;         // geo_neg_loss
        out[OUT_SCAL + 3] = lsh;        // loss_sharp
        out[OUT_SCAL + 4] = lcl;        // loss_cl
    }
}

extern "C" void kernel_launch(void* const* d_in, const int* in_sizes, int n_in,
                              void* d_out, int out_size, void* d_ws, size_t ws_size,
                              hipStream_t stream) {
    const float* q_geo   = (const float*)d_in[0];
    const float* q_cl    = (const float*)d_in[1];
    const float* geo_pos = (const float*)d_in[2];
    const float* cl_pos  = (const float*)d_in[3];
    const int*   label   = (const int*)d_in[4];
    const int*   idx     = (const int*)d_in[5];
    float* out = (float*)d_out;
    float* ws  = (float*)d_ws;

    mega<<<dim3(512), dim3(512), 0, stream>>>(q_geo, geo_pos, q_cl, cl_pos, label, idx, out, ws);
}

// Round 14
// 149.178 us; speedup vs baseline: 1.6395x; 1.6395x over previous
//
#include <hip/hip_runtime.h>
#include <math.h>

// Problem constants
#define BB 8
#define LL 1024
#define SS 1024
#define CC 128
#define NN 8
#define PP 256

static constexpr float EPS       = 1e-6f;
static constexpr float ONE_M_EPS = 1.0f - 1e-6f;
static constexpr float INV_T     = 1.0f / 0.07f;
static constexpr float NLL_MAX   = 13.815511f;    // -log(1e-6)
static constexpr float NLL_MIN   = 1.0000005e-6f; // -log(1-1e-6)

// Workspace layout (float offsets)
static constexpr size_t DOTSZ      = (size_t)BB * LL * SS;   // 8388608
static constexpr size_t OFF_LSER   = DOTSZ;                  // B*L
static constexpr size_t OFF_LSEC   = DOTSZ + 16384;          // B*S
static constexpr size_t OFF_SHARP2 = DOTSZ + 32768;          // B*L
static constexpr size_t OFF_RP     = DOTSZ + 40960;          // rowpart: 8*16*1024*4
static constexpr size_t OFF_CP     = OFF_RP + 524288;        // colpart: 8*16*1024*4
static constexpr size_t OFF_ACC    = OFF_CP + 524288;        // B*6
static constexpr size_t OFF_ACCCL  = OFF_ACC + 48;           // 2
static constexpr size_t OFF_QN     = OFF_ACC + 64;           // 8*128 normalized q_sel

// Output layout (floats): sharp1[8192], cl_pos_save[1024], scalars
static constexpr int OUT_CLSAVE = 8192;
static constexpr int OUT_SCAL   = 9216;

typedef __bf16 bf16x8 __attribute__((ext_vector_type(8)));
typedef float  floatx4 __attribute__((ext_vector_type(4)));

__device__ __forceinline__ bf16x8 mkfrag(unsigned a, unsigned b, unsigned c, unsigned d) {
    uint4 t = make_uint4(a, b, c, d);
    return __builtin_bit_cast(bf16x8, t);
}

// Split 4 fp32 into packed bf16 hi pairs (RNE) + lo pairs (exact residual).
__device__ __forceinline__ void split_f4(float4 x,
                                         unsigned& hp0, unsigned& hp1,
                                         unsigned& lp0, unsigned& lp1) {
    unsigned u0 = __builtin_bit_cast(unsigned, x.x);
    unsigned u1 = __builtin_bit_cast(unsigned, x.y);
    unsigned u2 = __builtin_bit_cast(unsigned, x.z);
    unsigned u3 = __builtin_bit_cast(unsigned, x.w);
    unsigned r0 = u0 + 0x7FFFu + ((u0 >> 16) & 1u);
    unsigned r1 = u1 + 0x7FFFu + ((u1 >> 16) & 1u);
    unsigned r2 = u2 + 0x7FFFu + ((u2 >> 16) & 1u);
    unsigned r3 = u3 + 0x7FFFu + ((u3 >> 16) & 1u);
    float s0 = x.x - __builtin_bit_cast(float, r0 & 0xFFFF0000u);
    float s1 = x.y - __builtin_bit_cast(float, r1 & 0xFFFF0000u);
    float s2 = x.z - __builtin_bit_cast(float, r2 & 0xFFFF0000u);
    float s3 = x.w - __builtin_bit_cast(float, r3 & 0xFFFF0000u);
    hp0 = __builtin_amdgcn_perm(r1, r0, 0x07060302u);
    hp1 = __builtin_amdgcn_perm(r3, r2, 0x07060302u);
    lp0 = __builtin_amdgcn_perm(__builtin_bit_cast(unsigned, s1),
                                __builtin_bit_cast(unsigned, s0), 0x07060302u);
    lp1 = __builtin_amdgcn_perm(__builtin_bit_cast(unsigned, s3),
                                __builtin_bit_cast(unsigned, s2), 0x07060302u);
}

// Read an 8-float fragment (k = q*8..q*8+7) from a swizzled LDS tile row and split.
// LDS tile: [128 rows][32 floats]; 16B chunk c stored at physical chunk c^(row&7).
__device__ __forceinline__ void frag_from_lds(const float* tile, int row, int q,
                                              bf16x8& hi, bf16x8& lo) {
    const float* rp = tile + row * 32;
    int sw = row & 7;
    float4 x0 = *(const float4*)(rp + (((q * 2)     ^ sw) * 4));
    float4 x1 = *(const float4*)(rp + (((q * 2 + 1) ^ sw) * 4));
    unsigned h0, h1, h2, h3, l0, l1, l2, l3;
    split_f4(x0, h0, h1, l0, l1);
    split_f4(x1, h2, h3, l2, l3);
    hi = mkfrag(h0, h1, h2, h3);
    lo = mkfrag(l0, l1, l2, l3);
}

// ---------------- K1: LDS-tiled GEMM (blocks 0..511) + prep (block 512) ----------------
// 128x128 tile per block, 4 waves (each 64x64), BK=32 fp32 double-buffered in LDS.
__global__ __launch_bounds__(256, 2) void gemm_dot(const float* __restrict__ A,
                                                   const float* __restrict__ Bm,
                                                   const float* __restrict__ q_cl,
                                                   const float* __restrict__ cl_pos,
                                                   const int* __restrict__ idx,
                                                   float* __restrict__ out,
                                                   float* __restrict__ dot,
                                                   float* __restrict__ ws) {
    __shared__ __align__(16) float ldsA[2][128 * 32];   // 2 x 16KB
    __shared__ __align__(16) float ldsB[2][128 * 32];   // 2 x 16KB

    int tid  = threadIdx.x;
    int lane = tid & 63;
    int w    = tid >> 6;

    if (blockIdx.x == 512) {
        // ---- prep: zero accumulators, normalize q_sel, write cl_pos_save ----
        if (tid < 52) ws[OFF_ACC + tid] = 0.0f;
        for (int n = w; n < NN; n += 4) {
            int in = idx[n];
            const float* q = q_cl + ((size_t)(n * PP + in)) * CC;
            float2 qv = *(const float2*)(q + 2 * lane);
            float ss = qv.x * qv.x + qv.y * qv.y;
            for (int o = 32; o; o >>= 1) ss += __shfl_xor(ss, o);
            float inv = 1.0f / fmaxf(sqrtf(ss), 1e-12f);
            *(float2*)(ws + OFF_QN + n * 128 + 2 * lane) = make_float2(qv.x * inv, qv.y * inv);
            const float* cp = cl_pos + ((size_t)(n * PP + in)) * CC;
            float2 cv = *(const float2*)(cp + 2 * lane);
            *(float2*)(out + OUT_CLSAVE + n * 128 + 2 * lane) = cv;
        }
        return;
    }

    int t  = blockIdx.x;            // 0..511
    int b  = t >> 6;
    int rm = t & 63;
    int bl = rm >> 3, bs = rm & 7;
    int R0 = bl * 128, C0 = bs * 128;

    const float* Ab = A  + ((size_t)b * LL + R0) * CC;
    const float* Bb = Bm + ((size_t)b * SS + C0) * CC;

    // Staging assignment: waves 0,1 -> A ; waves 2,3 -> B. Combined lane L = 0..127.
    const float* src  = (w >= 2) ? Bb : Ab;
    float* dst0 = (w >= 2) ? ldsB[0] : ldsA[0];
    float* dst1 = (w >= 2) ? ldsB[1] : ldsA[1];
    int L       = ((w & 1) << 6) | lane;
    int rowoff  = L >> 3;                       // 0..15
    int chunk   = L & 7;
    int swz4    = (chunk ^ (rowoff & 7)) * 4;   // physical chunk offset (floats)

    int fl   = lane & 15;
    int quad = lane >> 4;
    int wr   = w >> 1, wc = w & 1;              // wave's 64x64 quadrant
    int Rw   = wr * 64, Cw = wc * 64;           // local bases

    floatx4 acc[4][4];
#pragma unroll
    for (int i = 0; i < 4; i++)
#pragma unroll
        for (int j = 0; j < 4; j++) acc[i][j] = (floatx4){0.f, 0.f, 0.f, 0.f};

    float4 rg[8];
    // prologue: stage k-step 0
#pragma unroll
    for (int i = 0; i < 8; i++)
        rg[i] = *(const float4*)(src + (size_t)(i * 16 + rowoff) * CC + chunk * 4);
#pragma unroll
    for (int i = 0; i < 8; i++)
        *(float4*)(dst0 + (i * 16 + rowoff) * 32 + swz4) = rg[i];
    __syncthreads();

    for (int ks = 0; ks < 4; ks++) {
        const float* la = (ks & 1) ? ldsA[1] : ldsA[0];
        const float* lb = (ks & 1) ? ldsB[1] : ldsB[0];
        float* nxt = ((ks + 1) & 1) ? dst1 : dst0;
        if (ks < 3) {
            int k0 = (ks + 1) * 32;
#pragma unroll
            for (int i = 0; i < 8; i++)
                rg[i] = *(const float4*)(src + (size_t)(i * 16 + rowoff) * CC + k0 + chunk * 4);
        }
        // compute current buffer
        bf16x8 ah[4], al[4];
#pragma unroll
        for (int mt = 0; mt < 4; mt++)
            frag_from_lds(la, Rw + mt * 16 + fl, quad, ah[mt], al[mt]);
#pragma unroll
        for (int nt = 0; nt < 4; nt++) {
            bf16x8 bh, blo;
            frag_from_lds(lb, Cw + nt * 16 + fl, quad, bh, blo);
#pragma unroll
            for (int mt = 0; mt < 4; mt++) {
                acc[mt][nt] = __builtin_amdgcn_mfma_f32_16x16x32_bf16(ah[mt], bh,  acc[mt][nt], 0, 0, 0);
                acc[mt][nt] = __builtin_amdgcn_mfma_f32_16x16x32_bf16(ah[mt], blo, acc[mt][nt], 0, 0, 0);
                acc[mt][nt] = __builtin_amdgcn_mfma_f32_16x16x32_bf16(al[mt], bh,  acc[mt][nt], 0, 0, 0);
            }
        }
        if (ks < 3) {
#pragma unroll
            for (int i = 0; i < 8; i++)
                *(float4*)(nxt + (i * 16 + rowoff) * 32 + swz4) = rg[i];
        }
        __syncthreads();
    }

    // ---- Store dot tile. C/D layout: col=lane&15, row=quad*4+reg ----
#pragma unroll
    for (int mt = 0; mt < 4; mt++)
#pragma unroll
        for (int nt = 0; nt < 4; nt++) {
            int col = C0 + Cw + nt * 16 + fl;
#pragma unroll
            for (int r = 0; r < 4; r++) {
                int row = R0 + Rw + mt * 16 + quad * 4 + r;
                dot[((size_t)(b * 1024 + row)) * 1024 + col] = acc[mt][nt][r];
            }
        }

    // ---- Fused wave-private tile statistics (64x64 per wave) ----
    int stile = bs * 2 + wc;    // 64-col tile index 0..15
    int ltile = bl * 2 + wr;    // 64-row tile index 0..15
    float ces[4], cmx[4], csm[4], csq[4];
#pragma unroll
    for (int nt = 0; nt < 4; nt++) { ces[nt] = 0.f; cmx[nt] = -1e30f; csm[nt] = 0.f; csq[nt] = 0.f; }
#pragma unroll
    for (int mt = 0; mt < 4; mt++) {
#pragma unroll
        for (int r = 0; r < 4; r++) {
            float es = 0.f, mx = -1e30f, sm = 0.f, sq = 0.f;
#pragma unroll
            for (int nt = 0; nt < 4; nt++) {
                float d  = acc[mt][nt][r];
                float e  = __expf(d * INV_T);
                float s2 = fmaf(0.5f, d, 0.5f);
                es += e; mx = fmaxf(mx, s2); sm += s2; sq += s2 * s2;
                ces[nt] += e; cmx[nt] = fmaxf(cmx[nt], s2); csm[nt] += s2; csq[nt] += s2 * s2;
            }
            for (int o = 1; o < 16; o <<= 1) {
                es += __shfl_xor(es, o);
                mx = fmaxf(mx, __shfl_xor(mx, o));
                sm += __shfl_xor(sm, o);
                sq += __shfl_xor(sq, o);
            }
            if (fl == 0) {
                int row = R0 + Rw + mt * 16 + quad * 4 + r;
                *(float4*)(ws + OFF_RP + (((size_t)(b * 16 + stile)) * 1024 + row) * 4) =
                    make_float4(es, mx, sm, sq);
            }
        }
    }
#pragma unroll
    for (int nt = 0; nt < 4; nt++) {
        float es = ces[nt], mx = cmx[nt], sm = csm[nt], sq = csq[nt];
        for (int o = 16; o < 64; o <<= 1) {
            es += __shfl_xor(es, o);
            mx = fmaxf(mx, __shfl_xor(mx, o));
            sm += __shfl_xor(sm, o);
            sq += __shfl_xor(sq, o);
        }
        if (quad == 0) {
            int col = C0 + Cw + nt * 16 + fl;
            *(float4*)(ws + OFF_CP + (((size_t)(b * 16 + ltile)) * 1024 + col) * 4) =
                make_float4(es, mx, sm, sq);
        }
    }
}

// ---------------- K2: blocks 0..15 combine+softmax; blocks 16..527 contrast ----------------
__global__ __launch_bounds__(256) void mid(const float* __restrict__ cl_pos,
                                           const int* __restrict__ idx,
                                           float* __restrict__ ws,
                                           float* __restrict__ out) {
    int q   = blockIdx.x;
    int tid = threadIdx.x;
    int lane = tid & 63, wid = tid >> 6;

    if (q < 16) {
        bool docol = (q < 8);
        int b = q & 7;
        const float* part = ws + (docol ? OFF_CP : OFF_RP);
        float* lse = ws + (docol ? OFF_LSEC : OFF_LSER) + (size_t)b * 1024;
        float zs[4];
        float mxall = -1e30f;
#pragma unroll
        for (int r = 0; r < 4; r++) {
            int i = tid + r * 256;
            float es = 0.f, mx = -1e30f, sm = 0.f, sq = 0.f;
#pragma unroll
            for (int t = 0; t < 16; t++) {
                float4 v = *(const float4*)(part + (((size_t)(b * 16 + t)) * 1024 + i) * 4);
                es += v.x; mx = fmaxf(mx, v.y); sm += v.z; sq += v.w;
            }
            float mean = sm * (1.0f / 1024.0f);
            float var  = (sq - sm * sm * (1.0f / 1024.0f)) * (1.0f / 1023.0f);
            zs[r] = (mx - mean) / sqrtf(fmaxf(var, 1e-30f));
            mxall = fmaxf(mxall, zs[r]);
            lse[i] = __logf(es);
        }
        __shared__ float sb[4];
        __shared__ float red;
        float mx = mxall;
        for (int o = 32; o; o >>= 1) mx = fmaxf(mx, __shfl_xor(mx, o));
        if (!lane) sb[wid] = mx;
        __syncthreads();
        if (tid == 0) red = fmaxf(fmaxf(sb[0], sb[1]), fmaxf(sb[2], sb[3]));
        __syncthreads();
        mx = red;
        float e[4]; float smv = 0.f;
#pragma unroll
        for (int r = 0; r < 4; r++) { e[r] = __expf(zs[r] - mx); smv += e[r]; }
        for (int o = 32; o; o >>= 1) smv += __shfl_xor(smv, o);
        __syncthreads();
        if (!lane) sb[wid] = smv;
        __syncthreads();
        if (tid == 0) red = sb[0] + sb[1] + sb[2] + sb[3];
        __syncthreads();
        float inv = 1.0f / red;
        float* dst = docol ? (out + (size_t)b * 1024) : (ws + OFF_SHARP2 + (size_t)b * 1024);
#pragma unroll
        for (int r = 0; r < 4; r++) dst[tid + r * 256] = e[r] * inv;
    } else {
        // ---- contrast: one wave per all_k row j ----
        int j = (q - 16) * 4 + wid;
        int m, p;
        if (j < NN) {
            m = j; p = idx[j];
        } else {
            int jj = j - NN;
            m = jj / (PP - 1);
            p = 1 + (jj - m * (PP - 1));
            if (p == idx[m]) p = 0;
        }
        const float* k = cl_pos + ((size_t)(m * PP + p)) * CC;
        float2 kv = *(const float2*)(k + 2 * lane);
        float ksq = kv.x * kv.x + kv.y * kv.y;
        for (int o = 32; o; o >>= 1) ksq += __shfl_xor(ksq, o);
        float invkn = 1.0f / fmaxf(sqrtf(ksq), 1e-12f);
        float pos = 0.0f, neg = 0.0f;
        if (j < NN) {
            const float2 qv = *(const float2*)(ws + OFF_QN + j * 128 + 2 * lane);
            float dt = qv.x * kv.x + qv.y * kv.y;
            for (int o = 32; o; o >>= 1) dt += __shfl_xor(dt, o);
            float sim = fminf(fmaxf(fmaf(0.5f * invkn, dt, 0.5f), EPS), ONE_M_EPS);
            pos = -__logf(sim);
        } else {
#pragma unroll
            for (int n = 0; n < NN; n++) {
                const float2 qv = *(const float2*)(ws + OFF_QN + n * 128 + 2 * lane);
                float dt = qv.x * kv.x + qv.y * kv.y;
                for (int o = 32; o; o >>= 1) dt += __shfl_xor(dt, o);
                float om = fminf(fmaxf(fmaf(-0.5f * invkn, dt, 0.5f), EPS), ONE_M_EPS);
                neg -= __logf(om);
            }
        }
        __shared__ float cb[2][4];
        if (!lane) { cb[0][wid] = pos; cb[1][wid] = neg; }
        __syncthreads();
        if (tid == 0) {
            float ps = cb[0][0] + cb[0][1] + cb[0][2] + cb[0][3];
            float ng = cb[1][0] + cb[1][1] + cb[1][2] + cb[1][3];
            if (ps != 0.0f) atomicAdd(ws + OFF_ACCCL + 0, ps);
            if (ng != 0.0f) atomicAdd(ws + OFF_ACCCL + 1, ng);
        }
    }
}

// ---------------- K3: main elementwise loss (branchless) ----------------
__device__ __forceinline__ void proc_elem(float d, int lab, float lcj, float sh1j,
                                          float lr, float s2v,
                                          float& posg, float& negg, float& l1, float& l2,
                                          float& negs, float& pcf) {
    float t = lr + lcj - d * (2.0f * INV_T);   // -log(conf_geo)
    float isPos = (lab == 1) ? 1.0f : 0.0f;
    float isNeg = 1.0f - isPos;
    float tp   = fminf(fmaxf(t, NLL_MIN), NLL_MAX);
    float simc = fminf(fmaxf(fmaf(0.5f, d, 0.5f), EPS), ONE_M_EPS);
    float om   = fminf(fmaxf(fmaf(-0.5f, d, 0.5f), EPS), ONE_M_EPS);   // 1-simc exactly
    float nll2 = -__logf(simc);
    float cf   = fminf(fmaxf(__expf(-t), EPS), ONE_M_EPS);
    float nllg = -__logf(1.0f - cf);
    float nlls = -__logf(om);
    posg += isPos * tp;
    l1   += isPos * nll2 * sh1j;
    l2   += isPos * nll2 * s2v;
    pcf  += isPos;
    negg += isNeg * nllg;
    negs += isNeg * nlls;
}

__global__ __launch_bounds__(256) void main_loss(const float* __restrict__ dot,
                                                 const int* __restrict__ label,
                                                 const float* __restrict__ sharp1,
                                                 float* __restrict__ ws) {
    int b = blockIdx.y;
    int l0 = blockIdx.x * 4;
    int s = threadIdx.x * 4;
    float4 lc4 = *(const float4*)(ws + OFF_LSEC + (size_t)b * 1024 + s);
    float4 sh1 = *(const float4*)(sharp1 + (size_t)b * 1024 + s);
    const float* lser = ws + OFF_LSER + (size_t)b * 1024;
    const float* sh2  = ws + OFF_SHARP2 + (size_t)b * 1024;
    float posg = 0, negg = 0, l1 = 0, l2 = 0, negs = 0, pcf = 0;
#pragma unroll
    for (int r = 0; r < 4; r++) {
        int l = l0 + r;
        float lr  = lser[l];
        float s2v = sh2[l];
        size_t base = ((size_t)(b * 1024 + l)) * 1024 + s;
        float4 d4 = *(const float4*)(dot + base);
        int4  lb  = *(const int4*)(label + base);
        proc_elem(d4.x, lb.x, lc4.x, sh1.x, lr, s2v, posg, negg, l1, l2, negs, pcf);
        proc_elem(d4.y, lb.y, lc4.y, sh1.y, lr, s2v, posg, negg, l1, l2, negs, pcf);
        proc_elem(d4.z, lb.z, lc4.z, sh1.z, lr, s2v, posg, negg, l1, l2, negs, pcf);
        proc_elem(d4.w, lb.w, lc4.w, sh1.w, lr, s2v, posg, negg, l1, l2, negs, pcf);
    }
    float vals[6] = {posg, negg, l1, l2, negs, pcf};
    __shared__ float sb[6][4];
    int lane = threadIdx.x & 63, wid = threadIdx.x >> 6;
#pragma unroll
    for (int k = 0; k < 6; k++) {
        float v = vals[k];
        for (int o = 32; o; o >>= 1) v += __shfl_xor(v, o);
        if (!lane) sb[k][wid] = v;
    }
    __syncthreads();
    if (threadIdx.x < 6) {
        float r = sb[threadIdx.x][0] + sb[threadIdx.x][1] + sb[threadIdx.x][2] + sb[threadIdx.x][3];
        atomicAdd(ws + OFF_ACC + (size_t)b * 6 + threadIdx.x, r);
    }
}

// ---------------- K4: final scalar combine ----------------
__global__ void finalize(float* __restrict__ out, const float* __restrict__ ws) {
    if (threadIdx.x != 0) return;
    float gp = 0, gn = 0, lsh = 0;
    for (int b = 0; b < 8; b++) {
        const float* a = ws + OFF_ACC + (size_t)b * 6;
        float pc = a[5];
        float nc = (float)((size_t)LL * SS) - pc;
        gp += a[0] / fmaxf(pc, 1.0f);
        gn += a[1] / fmaxf(nc, 1.0f);
        lsh += (a[2] + a[3]) * 0.5f + a[4] / fmaxf(nc, 1.0f);
    }
    gp *= 0.125f; gn *= 0.125f; lsh *= 0.125f;
    float lgeo = gp + gn;
    float lgw = (0.5f * lgeo + 0.5f * lsh) * 0.5f;
    float clp = ws[OFF_ACCCL + 0] / 8.0f;
    float cln = ws[OFF_ACCCL + 1] / (8.0f * 2040.0f);
    float lcl = (clp + cln) * 0.5f * 0.5f;
    out[OUT_SCAL + 0] = lgw + lcl;  // total
    out[OUT_SCAL + 1] = gp;         // geo_pos_loss
    out[OUT_SCAL + 2] = gn;         // geo_neg_loss
    out[OUT_SCAL + 3] = lsh;        // loss_sharp
    out[OUT_SCAL + 4] = lcl;        // loss_cl
}

extern "C" void kernel_launch(void* const* d_in, const int* in_sizes, int n_in,
                              void* d_out, int out_size, void* d_ws, size_t ws_size,
                              hipStream_t stream) {
    const float* q_geo   = (const float*)d_in[0];
    const float* q_cl    = (const float*)d_in[1];
    const float* geo_pos = (const float*)d_in[2];
    const float* cl_pos  = (const float*)d_in[3];
    const int*   label   = (const int*)d_in[4];
    const int*   idx     = (const int*)d_in[5];
    float* out = (float*)d_out;
    float* ws  = (float*)d_ws;
    float* dot = ws;

    gemm_dot<<<dim3(513), dim3(256), 0, stream>>>(q_geo, geo_pos, q_cl, cl_pos, idx, out, dot, ws);
    mid<<<dim3(528), dim3(256), 0, stream>>>(cl_pos, idx, ws, out);
    main_loss<<<dim3(256, 8), dim3(256), 0, stream>>>(dot, label, out, ws);
    finalize<<<dim3(1), dim3(64), 0, stream>>>(out, ws);
}